// Round 7
// baseline (941.334 us; speedup 1.0000x reference)
//
#include <hip/hip_runtime.h>

// 3-layer LSTM (T=1024,B=512,F=32,H1=32,H2=8,H3=8) + locked dropout.
//
// R7: (1) REGISTER-PIN the weights. R2-R6 counters show VGPR_Count (92-136)
// below the declared weight-float count every round: the compiler
// rematerialized weights via in-loop global loads, which share the in-order
// vmcnt counter with the xg HBM prefetch -> every iteration waited ~HBM
// latency. asm("" : "+v"(w)) makes each weight an opaque VGPR def that
// cannot be rematerialized; __launch_bounds__(64,1) allows up to 512 VGPRs.
// (2) Fuse L2+L3 into half-waves (lanes 0-31 = L2's 32 gate rows, lanes
// 32-63 = L3's 32 rows; one 48-term dot over [h1|h2|h3] with per-lane
// weights, zero-padded) -> fewer DS ops (25->20) and less issue.
// (3) Unroll x2 for compile-time LDS parity. (4) xg pre-pass rebuilt:
// lane=row, weights in VGPRs, x via wave-uniform loads (s_load), coalesced
// stores -> memory-bound instead of LDS-throughput-bound.

constexpr int T = 1024, B = 512, F = 32;
constexpr int H1 = 32, H2 = 8, H3 = 8;
constexpr int G1 = 4 * H1;  // 128 gate rows, layer 1

#define WAVE_SYNC() asm volatile("" ::: "memory")
#define PIN(v) asm volatile("" : "+v"(v))

#if __has_builtin(__builtin_amdgcn_rcpf)
#define RCPF(x) __builtin_amdgcn_rcpf(x)
#else
#define RCPF(x) (1.0f / (x))
#endif
#if __has_builtin(__builtin_amdgcn_exp2f)
#define EXP2F(x) __builtin_amdgcn_exp2f(x)
#else
#define EXP2F(x) exp2f(x)
#endif

#define SIG_CM (-1.4426950408889634f)

__device__ __forceinline__ float act_f(float v, float cm, float ka, float kb) {
    return fmaf(ka, RCPF(1.0f + EXP2F(v * cm)), kb);
}
__device__ __forceinline__ float tanh_fast(float v) {
    return fmaf(2.0f, RCPF(1.0f + EXP2F(v * (2.0f * SIG_CM))), -1.0f);
}

// macro params avoid float4 member names x/y/z/w (R1 lesson)
#define FMA4(ACC, WARR, VEC, BASE)                                             \
    ACC = fmaf(WARR[(BASE) + 0], VEC.x, ACC);                                  \
    ACC = fmaf(WARR[(BASE) + 1], VEC.y, ACC);                                  \
    ACC = fmaf(WARR[(BASE) + 2], VEC.z, ACC);                                  \
    ACC = fmaf(WARR[(BASE) + 3], VEC.w, ACC);

// ---------------------------------------------------------------------------
// Kernel A: xg[(t*B+b)*128 + r] = dot(Wih1[r], x[t][b]) + bih1[r] + bhh1[r]
// 128 threads/block (thread = gate row), 64 (t,b) pairs/block, 8192 blocks.
// Weights live in VGPRs (32/thread); x is read via wave-uniform addresses
// (scalar loads); stores are 512B-coalesced. Memory-bound by the 256 MB write.
// ---------------------------------------------------------------------------
constexpr int GPB = 64;  // (t,b) pairs per block

__global__ __launch_bounds__(128) void xg_kernel(
    const float* __restrict__ x, const float* __restrict__ Wih1,
    const float* __restrict__ bih1, const float* __restrict__ bhh1,
    float* __restrict__ xg)
{
    const int tid = threadIdx.x;       // gate row 0..127
    const int pair0 = blockIdx.x * GPB;

    float w[F];
#pragma unroll
    for (int k = 0; k < F; ++k) w[k] = Wih1[tid * F + k];
    const float bias = bih1[tid] + bhh1[tid];

#pragma unroll 2
    for (int p = 0; p < GPB; ++p) {
        // wave-uniform address -> scalar loads
        const float4* xp4 = (const float4*)(x + (size_t)(pair0 + p) * F);
        float acc = bias;
#pragma unroll
        for (int q = 0; q < 8; ++q) {
            const float4 xv = xp4[q];
            acc = fmaf(w[4 * q + 0], xv.x, acc);
            acc = fmaf(w[4 * q + 1], xv.y, acc);
            acc = fmaf(w[4 * q + 2], xv.z, acc);
            acc = fmaf(w[4 * q + 3], xv.w, acc);
        }
        xg[(size_t)(pair0 + p) * G1 + tid] = acc;  // 512B coalesced
    }
}

// ---------------------------------------------------------------------------
// Kernel B: skewed recurrent scan, one wave per batch element.
// iter i: L1(i) | fused{ L2(i-1) in lanes 0-31, L3(i-2) in lanes 32-63 }.
// ---------------------------------------------------------------------------
__global__ __launch_bounds__(64, 1) void lstm3_rec_kernel(
    const float* __restrict__ xg,
    const float* __restrict__ Whh1,
    const float* __restrict__ Wih2, const float* __restrict__ Whh2,
    const float* __restrict__ bih2, const float* __restrict__ bhh2,
    const float* __restrict__ Wih3, const float* __restrict__ Whh3,
    const float* __restrict__ bih3, const float* __restrict__ bhh3,
    const float* __restrict__ mask1, const float* __restrict__ mask2,
    const float* __restrict__ mask3,
    float* __restrict__ out)
{
    const int lane = threadIdx.x;
    const int b = blockIdx.x;

    __shared__ __align__(16) float sh_h1[2][H1];
    __shared__ __align__(16) float sh23[2][16];  // [par][0..7]=h2, [8..15]=h3

    // ---------------- weights (to be PINNED into VGPRs) ----------------
    float wh1a[H1], wh1b[H1];
#pragma unroll
    for (int k = 0; k < H1; ++k) {
        wh1a[k] = Whh1[lane * H1 + k];          // row lane      (i|f half)
        wh1b[k] = Whh1[(lane + 64) * H1 + k];   // row lane+64   (g|o half)
    }
    float cm1b = (lane < 32) ? 2.0f * SIG_CM : SIG_CM;
    float ka1b = (lane < 32) ? 2.0f : 1.0f;
    float kb1b = (lane < 32) ? -1.0f : 0.0f;

    // fused L2/L3: 48-term dot over [h1(32) | h2(8) | h3(8)]
    const int r = lane & 31;
    const bool lower = (lane < 32);
    float w23[48];
    if (lower) {  // L2 gate row r
#pragma unroll
        for (int k = 0; k < H1; ++k) w23[k] = Wih2[r * H1 + k] * mask1[b * H1 + k];
#pragma unroll
        for (int k = 0; k < H2; ++k) w23[32 + k] = Whh2[r * H2 + k];
#pragma unroll
        for (int k = 0; k < H3; ++k) w23[40 + k] = 0.0f;
    } else {      // L3 gate row r
#pragma unroll
        for (int k = 0; k < H1; ++k) w23[k] = 0.0f;
#pragma unroll
        for (int k = 0; k < H2; ++k) w23[32 + k] = Wih3[r * H2 + k] * mask2[b * H2 + k];
#pragma unroll
        for (int k = 0; k < H3; ++k) w23[40 + k] = Whh3[r * H3 + k];
    }
    float bias23 = lower ? (bih2[r] + bhh2[r]) : (bih3[r] + bhh3[r]);
    const int sec = r >> 3;  // 0=i 1=f 2=g 3=o
    float cm23 = (sec == 2) ? 2.0f * SIG_CM : SIG_CM;
    float ka23 = (sec == 2) ? 2.0f : 1.0f;
    float kb23 = (sec == 2) ? -1.0f : 0.0f;
    float m3 = mask3[b * H3 + (lane & 7)];
    const int thresh = lower ? 1 : 2;  // first iter the c-update is live

    // PIN: opaque defs -> compiler cannot rematerialize via in-loop loads
#pragma unroll
    for (int k = 0; k < H1; ++k) { PIN(wh1a[k]); PIN(wh1b[k]); }
#pragma unroll
    for (int k = 0; k < 48; ++k) PIN(w23[k]);
    PIN(cm1b); PIN(ka1b); PIN(kb1b);
    PIN(bias23); PIN(cm23); PIN(ka23); PIN(kb23); PIN(m3);

    // ---------------- state init ----------------
    float c1 = 0.f, c23 = 0.f;
    if (lane < H1) { sh_h1[0][lane] = 0.f; sh_h1[1][lane] = 0.f; }
    if (lane < 16) { sh23[0][lane] = 0.f; sh23[1][lane] = 0.f; }
    WAVE_SYNC();

    const int xoff = b * G1 + lane;
    const int gbase = (lane & 32) + (lane & 7);  // shfl base for gate gather

    // xg prefetch ring, distance 4 (covers HBM miss even at ~500 cyc/iter)
    float xA0 = xg[(size_t)(0 << 16) + xoff], xB0 = xg[(size_t)(0 << 16) + xoff + 64];
    float xA1 = xg[(size_t)(1 << 16) + xoff], xB1 = xg[(size_t)(1 << 16) + xoff + 64];
    float xA2 = xg[(size_t)(2 << 16) + xoff], xB2 = xg[(size_t)(2 << 16) + xoff + 64];
    float xA3 = xg[(size_t)(3 << 16) + xoff], xB3 = xg[(size_t)(3 << 16) + xoff + 64];

    auto step = [&](int i, int par, float xa, float xb, float& pfa, float& pfb) {
        // prefetch xg(i+4)
        {
            int tp = i + 4; tp = (tp < T) ? tp : (T - 1);
            const float* xgp = xg + ((size_t)tp << 16) + xoff;
            pfa = xgp[0];
            pfb = xgp[64];
        }

        // ---- all LDS reads at top (prev-iteration state) ----
        const float4* h1p = (const float4*)sh_h1[par ^ 1];
        const float4 hv0 = h1p[0], hv1 = h1p[1], hv2 = h1p[2], hv3 = h1p[3];
        const float4 hv4 = h1p[4], hv5 = h1p[5], hv6 = h1p[6], hv7 = h1p[7];
        const float4* up = (const float4*)sh23[par ^ 1];
        const float4 u0 = up[0], u1 = up[1], u2 = up[2], u3 = up[3];

        // ================= L1(i): rows lane & lane+64 =================
        float a0A = 0.f, a0B = 0.f, a0C = 0.f, a0D = 0.f;
        float a1A = 0.f, a1B = 0.f, a1C = 0.f, a1D = 0.f;
        FMA4(a0A, wh1a, hv0, 0);  FMA4(a0B, wh1a, hv1, 4);
        FMA4(a0C, wh1a, hv2, 8);  FMA4(a0D, wh1a, hv3, 12);
        FMA4(a0A, wh1a, hv4, 16); FMA4(a0B, wh1a, hv5, 20);
        FMA4(a0C, wh1a, hv6, 24); FMA4(a0D, wh1a, hv7, 28);
        FMA4(a1A, wh1b, hv0, 0);  FMA4(a1B, wh1b, hv1, 4);
        FMA4(a1C, wh1b, hv2, 8);  FMA4(a1D, wh1b, hv3, 12);
        FMA4(a1A, wh1b, hv4, 16); FMA4(a1B, wh1b, hv5, 20);
        FMA4(a1C, wh1b, hv6, 24); FMA4(a1D, wh1b, hv7, 28);
        const float a0 = xa + (a0A + a0B) + (a0C + a0D);
        const float a1 = xb + (a1A + a1B) + (a1C + a1D);
        const float g0 = act_f(a0, SIG_CM, 1.0f, 0.0f);  // i (l<32) / f (l>=32)
        const float g1 = act_f(a1, cm1b, ka1b, kb1b);    // g (l<32) / o (l>=32)
        const float f_ = __shfl_xor(g0, 32);
        const float o_ = __shfl_xor(g1, 32);
        c1 = fmaf(f_, c1, g0 * g1);
        const float h1new = o_ * tanh_fast(c1);

        // ===== fused L2(i-1) [lanes 0-31] / L3(i-2) [lanes 32-63] =====
        float s0 = 0.f, s1 = 0.f, s2 = 0.f, s3 = 0.f;
        FMA4(s0, w23, hv0, 0);  FMA4(s0, w23, hv1, 4);  FMA4(s0, w23, hv2, 8);
        FMA4(s1, w23, hv3, 12); FMA4(s1, w23, hv4, 16); FMA4(s1, w23, hv5, 20);
        FMA4(s2, w23, hv6, 24); FMA4(s2, w23, hv7, 28); FMA4(s2, w23, u0, 32);
        FMA4(s3, w23, u1, 36);  FMA4(s3, w23, u2, 40);  FMA4(s3, w23, u3, 44);
        const float a23 = bias23 + (s0 + s1) + (s2 + s3);
        const float rv = act_f(a23, cm23, ka23, kb23);
        const float gi = __shfl(rv, gbase);
        const float gf = __shfl(rv, gbase + 8);
        const float gg = __shfl(rv, gbase + 16);
        const float go = __shfl(rv, gbase + 24);
        const bool on = (i >= thresh);
        c23 = on ? fmaf(gf, c23, gi * gg) : 0.0f;
        const float hnew = go * tanh_fast(c23);  // h2new (lower) / h3new (upper)

        // out(t3 = i-2) from lanes 32-39
        if (i >= 2 && (lane & 56) == 32)
            out[(i - 2) * (B * H3) + b * H3 + (lane & 7)] = hnew * m3;

        // ---- writes at bottom ----
        if (lane < H1) sh_h1[par][lane] = h1new;
        if ((lane & 24) == 0)  // lanes 0-7 -> h2, lanes 32-39 -> h3
            sh23[par][(lane & 7) | ((lane & 32) >> 2)] = hnew;
    };

    for (int i = 0; i < T + 2; i += 2) {
        float tA0, tB0, tA1, tB1;
        step(i,     0, xA0, xB0, tA0, tB0);
        step(i + 1, 1, xA1, xB1, tA1, tB1);
        xA0 = xA2; xB0 = xB2; xA1 = xA3; xB1 = xB3;
        xA2 = tA0; xB2 = tB0; xA3 = tA1; xB3 = tB1;
    }
}

// ---------------------------------------------------------------------------
// Fallback (R3 structure, self-contained): used iff ws_size too small.
// ---------------------------------------------------------------------------
__global__ __launch_bounds__(64, 1) void lstm3_fallback_kernel(
    const float* __restrict__ x,
    const float* __restrict__ Wih1, const float* __restrict__ Whh1,
    const float* __restrict__ bih1, const float* __restrict__ bhh1,
    const float* __restrict__ Wih2, const float* __restrict__ Whh2,
    const float* __restrict__ bih2, const float* __restrict__ bhh2,
    const float* __restrict__ Wih3, const float* __restrict__ Whh3,
    const float* __restrict__ bih3, const float* __restrict__ bhh3,
    const float* __restrict__ mask1, const float* __restrict__ mask2,
    const float* __restrict__ mask3,
    float* __restrict__ out)
{
    const int lane = threadIdx.x;
    const int b = blockIdx.x;

    __shared__ __align__(16) float sh_x[2][F];
    __shared__ __align__(16) float sh_h1[H1];
    __shared__ __align__(16) float sh_h2[H2];
    __shared__ __align__(16) float sh_h3[H3];

    const int r0 = lane, r1 = lane + 64;
    float wi1a[F], wh1a[H1], wi1b[F], wh1b[H1];
#pragma unroll
    for (int k = 0; k < F; ++k) { wi1a[k] = Wih1[r0 * F + k]; wi1b[k] = Wih1[r1 * F + k]; }
#pragma unroll
    for (int k = 0; k < H1; ++k) { wh1a[k] = Whh1[r0 * H1 + k]; wh1b[k] = Whh1[r1 * H1 + k]; }
    const float bias0 = bih1[r0] + bhh1[r0];
    const float bias1 = bih1[r1] + bhh1[r1];
    const float cm1b = (lane < 32) ? 2.0f * SIG_CM : SIG_CM;
    const float ka1b = (lane < 32) ? 2.0f : 1.0f;
    const float kb1b = (lane < 32) ? -1.0f : 0.0f;

    const int r2 = lane & 31;
    float wi2[H1], wh2[H2];
#pragma unroll
    for (int k = 0; k < H1; ++k) wi2[k] = Wih2[r2 * H1 + k] * mask1[b * H1 + k];
#pragma unroll
    for (int k = 0; k < H2; ++k) wh2[k] = Whh2[r2 * H2 + k];
    const float bias2 = bih2[r2] + bhh2[r2];
    const int sec2 = r2 >> 3;
    const float cm2 = (sec2 == 2) ? 2.0f * SIG_CM : SIG_CM;
    const float ka2 = (sec2 == 2) ? 2.0f : 1.0f;
    const float kb2 = (sec2 == 2) ? -1.0f : 0.0f;

    float wi3[H2], wh3[H3];
#pragma unroll
    for (int k = 0; k < H2; ++k) wi3[k] = Wih3[r2 * H2 + k] * mask2[b * H2 + k];
#pragma unroll
    for (int k = 0; k < H3; ++k) wh3[k] = Whh3[r2 * H3 + k];
    const float bias3 = bih3[r2] + bhh3[r2];

    const float m3 = mask3[b * H3 + (lane & 7)];

    float c1 = 0.f, c2 = 0.f, c3 = 0.f;
    if (lane < F) sh_x[0][lane] = x[b * F + lane];
    if (lane < H1) sh_h1[lane] = 0.f;
    if (lane < H2) sh_h2[lane] = 0.f;
    if (lane < H3) sh_h3[lane] = 0.f;
    WAVE_SYNC();

    const int j = lane & 7;

    for (int t = 0; t < T; ++t) {
        const int cur = t & 1, nxt = cur ^ 1;
        float xnext = 0.f;
        {
            const int tn = (t + 1 < T) ? (t + 1) : t;
            if (lane < F) xnext = x[tn * (B * F) + b * F + lane];
        }
        float a0x = 0.f, a0h = 0.f, a1x = 0.f, a1h = 0.f;
        {
            const float4* xp = (const float4*)sh_x[cur];
            const float4* hp = (const float4*)sh_h1;
#pragma unroll
            for (int q = 0; q < 8; ++q) {
                float4 xv = xp[q], hv = hp[q];
                FMA4(a0x, wi1a, xv, 4 * q);
                FMA4(a0h, wh1a, hv, 4 * q);
                FMA4(a1x, wi1b, xv, 4 * q);
                FMA4(a1h, wh1b, hv, 4 * q);
            }
        }
        const float a0 = bias0 + a0x + a0h;
        const float a1 = bias1 + a1x + a1h;
        const float g0 = act_f(a0, SIG_CM, 1.0f, 0.0f);
        const float g1 = act_f(a1, cm1b, ka1b, kb1b);
        const float f_ = __shfl_xor(g0, 32);
        const float o_ = __shfl_xor(g1, 32);
        c1 = fmaf(f_, c1, g0 * g1);
        const float h1 = o_ * tanh_fast(c1);

        WAVE_SYNC();
        if (lane < H1) sh_h1[lane] = h1;
        if (lane < F) sh_x[nxt][lane] = xnext;
        WAVE_SYNC();

        float a2x = 0.f, a2h = 0.f;
        {
            const float4* hp = (const float4*)sh_h1;
#pragma unroll
            for (int q = 0; q < 8; ++q) { float4 hv = hp[q]; FMA4(a2x, wi2, hv, 4 * q); }
            const float4* h2p = (const float4*)sh_h2;
            float4 v0 = h2p[0], v1 = h2p[1];
            FMA4(a2h, wh2, v0, 0);
            FMA4(a2h, wh2, v1, 4);
        }
        const float a2 = bias2 + a2x + a2h;
        const float r2v = act_f(a2, cm2, ka2, kb2);
        const float i2 = __shfl(r2v, j);
        const float f2 = __shfl(r2v, j + 8);
        const float g2 = __shfl(r2v, j + 16);
        const float o2 = __shfl(r2v, j + 24);
        c2 = fmaf(f2, c2, i2 * g2);
        const float h2 = o2 * tanh_fast(c2);

        WAVE_SYNC();
        if (lane < H2) sh_h2[lane] = h2;
        WAVE_SYNC();

        float a3x = 0.f, a3h = 0.f;
        {
            const float4* h2p = (const float4*)sh_h2;
            const float4* h3p = (const float4*)sh_h3;
            float4 u0 = h2p[0], u1 = h2p[1];
            FMA4(a3x, wi3, u0, 0);
            FMA4(a3x, wi3, u1, 4);
            float4 w0 = h3p[0], w1 = h3p[1];
            FMA4(a3h, wh3, w0, 0);
            FMA4(a3h, wh3, w1, 4);
        }
        const float a3 = bias3 + a3x + a3h;
        const float r3v = act_f(a3, cm2, ka2, kb2);
        const float i3 = __shfl(r3v, j);
        const float f3 = __shfl(r3v, j + 8);
        const float g3 = __shfl(r3v, j + 16);
        const float o3 = __shfl(r3v, j + 24);
        c3 = fmaf(f3, c3, i3 * g3);
        const float h3 = o3 * tanh_fast(c3);

        if (lane < H3) out[t * (B * H3) + b * H3 + lane] = h3 * m3;

        WAVE_SYNC();
        if (lane < H3) sh_h3[lane] = h3;
        WAVE_SYNC();
    }
}

extern "C" void kernel_launch(void* const* d_in, const int* in_sizes, int n_in,
                              void* d_out, int out_size, void* d_ws, size_t ws_size,
                              hipStream_t stream) {
    (void)in_sizes; (void)n_in; (void)out_size;
    const float* x     = (const float*)d_in[0];
    const float* Wih1  = (const float*)d_in[1];
    const float* Whh1  = (const float*)d_in[2];
    const float* bih1  = (const float*)d_in[3];
    const float* bhh1  = (const float*)d_in[4];
    const float* Wih2  = (const float*)d_in[5];
    const float* Whh2  = (const float*)d_in[6];
    const float* bih2  = (const float*)d_in[7];
    const float* bhh2  = (const float*)d_in[8];
    const float* Wih3  = (const float*)d_in[9];
    const float* Whh3  = (const float*)d_in[10];
    const float* bih3  = (const float*)d_in[11];
    const float* bhh3  = (const float*)d_in[12];
    const float* mask1 = (const float*)d_in[13];
    const float* mask2 = (const float*)d_in[14];
    const float* mask3 = (const float*)d_in[15];
    float* out = (float*)d_out;

    const size_t xg_bytes = (size_t)T * B * G1 * sizeof(float);  // 256 MB
    if (ws_size >= xg_bytes) {
        float* xg = (float*)d_ws;
        xg_kernel<<<dim3(T * B / GPB), dim3(128), 0, stream>>>(
            x, Wih1, bih1, bhh1, xg);
        lstm3_rec_kernel<<<dim3(B), dim3(64), 0, stream>>>(
            xg, Whh1, Wih2, Whh2, bih2, bhh2,
            Wih3, Whh3, bih3, bhh3, mask1, mask2, mask3, out);
    } else {
        lstm3_fallback_kernel<<<dim3(B), dim3(64), 0, stream>>>(
            x, Wih1, Whh1, bih1, bhh1, Wih2, Whh2, bih2, bhh2,
            Wih3, Whh3, bih3, bhh3, mask1, mask2, mask3, out);
    }
}

// Round 8
// 813.138 us; speedup vs baseline: 1.1577x; 1.1577x over previous
//
#include <hip/hip_runtime.h>

// 3-layer LSTM (T=1024,B=512,F=32,H1=32,H2=8,H3=8) + locked dropout.
//
// R8: WEIGHTS OUT OF THE REGISTER FIGHT.
// R5-R7 evidence: compiler caps VGPRs ~100 and spills per-lane weight arrays
// to scratch no matter what (PIN included); in-loop scratch reloads share the
// in-order vmcnt counter with the xg HBM prefetch -> every wait on a reload
// drains the prefetch -> ~1400 cyc/step. Fix:
//  - L1 weights (Whh1, 64 floats/lane) live in LDS, lane-interleaved
//    float4 layout sA/sB[q][lane] -> wave-wide ds_read_b128 at the full
//    128 B/clk floor, no vmcnt. Per-step memory clobber stops the compiler
//    from hoisting them back into registers.
//  - Only w23 (48 floats) + xg ring stay in registers (~90 live -> no spill).
//  - xg prefetch is now the ONLY in-loop vmem -> distance-4 ring works.
//  - xg pre-pass rebuilt: thread=row, 32 reg weights, x staged via LDS
//    (coalesced), broadcast reads, coalesced stores.

constexpr int T = 1024, B = 512, F = 32;
constexpr int H1 = 32, H2 = 8, H3 = 8;
constexpr int G1 = 4 * H1;  // 128 gate rows, layer 1

#define WAVE_SYNC() asm volatile("" ::: "memory")
#define PIN(v) asm volatile("" : "+v"(v))

#if __has_builtin(__builtin_amdgcn_rcpf)
#define RCPF(x) __builtin_amdgcn_rcpf(x)
#else
#define RCPF(x) (1.0f / (x))
#endif
#if __has_builtin(__builtin_amdgcn_exp2f)
#define EXP2F(x) __builtin_amdgcn_exp2f(x)
#else
#define EXP2F(x) exp2f(x)
#endif

#define SIG_CM (-1.4426950408889634f)

__device__ __forceinline__ float act_f(float v, float cm, float ka, float kb) {
    return fmaf(ka, RCPF(1.0f + EXP2F(v * cm)), kb);
}
__device__ __forceinline__ float tanh_fast(float v) {
    return fmaf(2.0f, RCPF(1.0f + EXP2F(v * (2.0f * SIG_CM))), -1.0f);
}

// macro params avoid float4 member names x/y/z/w (R1 lesson)
#define FMA4(ACC, WARR, VEC, BASE)                                             \
    ACC = fmaf(WARR[(BASE) + 0], VEC.x, ACC);                                  \
    ACC = fmaf(WARR[(BASE) + 1], VEC.y, ACC);                                  \
    ACC = fmaf(WARR[(BASE) + 2], VEC.z, ACC);                                  \
    ACC = fmaf(WARR[(BASE) + 3], VEC.w, ACC);

#define DOT4(ACC, WV, VV)                                                      \
    ACC = fmaf(WV.x, VV.x, ACC);                                               \
    ACC = fmaf(WV.y, VV.y, ACC);                                               \
    ACC = fmaf(WV.z, VV.z, ACC);                                               \
    ACC = fmaf(WV.w, VV.w, ACC);

// ---------------------------------------------------------------------------
// Kernel A: xg[(t*B+b)*128 + r] = dot(Wih1[r], x[t][b]) + bih1[r] + bhh1[r]
// 128 threads (= 128 rows) / block; GPB pairs staged via LDS per block.
// Weights: 32 floats in registers per thread (no spill). x: coalesced into
// LDS, then broadcast reads. Stores 512B-coalesced per pair.
// ---------------------------------------------------------------------------
constexpr int GPB = 64;  // (t,b) pairs per block

__global__ __launch_bounds__(128) void xg_kernel(
    const float* __restrict__ x, const float* __restrict__ Wih1,
    const float* __restrict__ bih1, const float* __restrict__ bhh1,
    float* __restrict__ xg)
{
    __shared__ __align__(16) float4 sx4[GPB * 8];  // 64 pairs x 32 floats = 8KB

    const int tid = threadIdx.x;       // gate row 0..127
    const int pair0 = blockIdx.x * GPB;

    float4 w4[8];
#pragma unroll
    for (int q = 0; q < 8; ++q) w4[q] = ((const float4*)Wih1)[tid * 8 + q];
    const float bias = bih1[tid] + bhh1[tid];

    for (int d = tid; d < GPB * 8; d += 128)
        sx4[d] = ((const float4*)x)[(size_t)pair0 * 8 + d];  // coalesced
    __syncthreads();

    for (int p = 0; p < GPB; ++p) {
        float acc = bias;
#pragma unroll
        for (int q = 0; q < 8; ++q) {
            const float4 xv = sx4[p * 8 + q];  // broadcast (uniform addr)
            DOT4(acc, w4[q], xv);
        }
        xg[(size_t)(pair0 + p) * G1 + tid] = acc;  // 512B coalesced
    }
}

// ---------------------------------------------------------------------------
// Kernel B: skewed recurrent scan, one wave per batch element.
// iter i: L1(i) | fused{ L2(i-1) in lanes 0-31, L3(i-2) in lanes 32-63 }.
// L1 weights in LDS (lane-interleaved float4), w23 in registers.
// ---------------------------------------------------------------------------
__global__ __launch_bounds__(64, 1) void lstm3_rec_kernel(
    const float* __restrict__ xg,
    const float* __restrict__ Whh1,
    const float* __restrict__ Wih2, const float* __restrict__ Whh2,
    const float* __restrict__ bih2, const float* __restrict__ bhh2,
    const float* __restrict__ Wih3, const float* __restrict__ Whh3,
    const float* __restrict__ bih3, const float* __restrict__ bhh3,
    const float* __restrict__ mask1, const float* __restrict__ mask2,
    const float* __restrict__ mask3,
    float* __restrict__ out)
{
    const int lane = threadIdx.x;
    const int b = blockIdx.x;

    // sA[q][l] = Whh1 row l,     cols 4q..4q+3   (rows 0..63:   i|f half)
    // sB[q][l] = Whh1 row l+64,  cols 4q..4q+3   (rows 64..127: g|o half)
    __shared__ __align__(16) float4 sA[8][64];
    __shared__ __align__(16) float4 sB[8][64];
    __shared__ __align__(16) float sh_h1[2][H1];
    __shared__ __align__(16) float sh23[2][16];  // [par][0..7]=h2, [8..15]=h3

    // ---- stage Whh1 into LDS (coalesced float4 global reads, one-time) ----
    for (int d = lane; d < G1 * 8; d += 64) {     // 1024 float4s
        const float4 wv = ((const float4*)Whh1)[d];
        const int r = d >> 3, q = d & 7;
        if (r < 64) sA[q][r] = wv; else sB[q][r - 64] = wv;
    }

    float cm1b = (lane < 32) ? 2.0f * SIG_CM : SIG_CM;
    float ka1b = (lane < 32) ? 2.0f : 1.0f;
    float kb1b = (lane < 32) ? -1.0f : 0.0f;

    // fused L2/L3: 48-term dot over [h1(32) | h2(8) | h3(8)]
    const int r = lane & 31;
    const bool lower = (lane < 32);
    float w23[48];
    if (lower) {  // L2 gate row r
#pragma unroll
        for (int k = 0; k < H1; ++k) w23[k] = Wih2[r * H1 + k] * mask1[b * H1 + k];
#pragma unroll
        for (int k = 0; k < H2; ++k) w23[32 + k] = Whh2[r * H2 + k];
#pragma unroll
        for (int k = 0; k < H3; ++k) w23[40 + k] = 0.0f;
    } else {      // L3 gate row r
#pragma unroll
        for (int k = 0; k < H1; ++k) w23[k] = 0.0f;
#pragma unroll
        for (int k = 0; k < H2; ++k) w23[32 + k] = Wih3[r * H2 + k] * mask2[b * H2 + k];
#pragma unroll
        for (int k = 0; k < H3; ++k) w23[40 + k] = Whh3[r * H3 + k];
    }
    float bias23 = lower ? (bih2[r] + bhh2[r]) : (bih3[r] + bhh3[r]);
    const int sec = r >> 3;  // 0=i 1=f 2=g 3=o
    float cm23 = (sec == 2) ? 2.0f * SIG_CM : SIG_CM;
    float ka23 = (sec == 2) ? 2.0f : 1.0f;
    float kb23 = (sec == 2) ? -1.0f : 0.0f;
    float m3 = mask3[b * H3 + (lane & 7)];
    const int thresh = lower ? 1 : 2;

#pragma unroll
    for (int k = 0; k < 48; ++k) PIN(w23[k]);
    PIN(cm1b); PIN(ka1b); PIN(kb1b);
    PIN(bias23); PIN(cm23); PIN(ka23); PIN(kb23); PIN(m3);

    // ---- state init ----
    float c1 = 0.f, c23 = 0.f;
    if (lane < H1) { sh_h1[0][lane] = 0.f; sh_h1[1][lane] = 0.f; }
    if (lane < 16) { sh23[0][lane] = 0.f; sh23[1][lane] = 0.f; }
    WAVE_SYNC();

    const int xoff = b * G1 + lane;
    const int gbase = (lane & 32) + (lane & 7);  // shfl base for gate gather

    // xg prefetch ring, distance 4 (only in-loop vmem -> vmcnt uncoupled)
    float xA0 = xg[(size_t)(0 << 16) + xoff], xB0 = xg[(size_t)(0 << 16) + xoff + 64];
    float xA1 = xg[(size_t)(1 << 16) + xoff], xB1 = xg[(size_t)(1 << 16) + xoff + 64];
    float xA2 = xg[(size_t)(2 << 16) + xoff], xB2 = xg[(size_t)(2 << 16) + xoff + 64];
    float xA3 = xg[(size_t)(3 << 16) + xoff], xB3 = xg[(size_t)(3 << 16) + xoff + 64];

    auto step = [&](int i, int par, float xa, float xb, float& pfa, float& pfb) {
        // memory clobber: forces per-step LDS weight reads (prevents the
        // compiler from hoisting them into registers and spilling again)
        WAVE_SYNC();

        // prefetch xg(i+4)
        {
            int tp = i + 4; tp = (tp < T) ? tp : (T - 1);
            const float* xgp = xg + ((size_t)tp << 16) + xoff;
            pfa = xgp[0];
            pfb = xgp[64];
        }

        // ---- state reads (broadcast) ----
        const float4* h1p = (const float4*)sh_h1[par ^ 1];
        const float4 hv0 = h1p[0], hv1 = h1p[1], hv2 = h1p[2], hv3 = h1p[3];
        const float4 hv4 = h1p[4], hv5 = h1p[5], hv6 = h1p[6], hv7 = h1p[7];
        const float4* up = (const float4*)sh23[par ^ 1];
        const float4 u0 = up[0], u1 = up[1], u2 = up[2], u3 = up[3];

        // ================= L1(i): rows lane & lane+64 =================
        // weights from LDS, full-BW interleaved b128 reads
        float a0A = 0.f, a0B = 0.f, a0C = 0.f, a0D = 0.f;
        {
            const float4 wa0 = sA[0][lane], wa1 = sA[1][lane];
            const float4 wa2 = sA[2][lane], wa3 = sA[3][lane];
            const float4 wa4 = sA[4][lane], wa5 = sA[5][lane];
            const float4 wa6 = sA[6][lane], wa7 = sA[7][lane];
            DOT4(a0A, wa0, hv0); DOT4(a0B, wa1, hv1);
            DOT4(a0C, wa2, hv2); DOT4(a0D, wa3, hv3);
            DOT4(a0A, wa4, hv4); DOT4(a0B, wa5, hv5);
            DOT4(a0C, wa6, hv6); DOT4(a0D, wa7, hv7);
        }
        float a1A = 0.f, a1B = 0.f, a1C = 0.f, a1D = 0.f;
        {
            const float4 wb0 = sB[0][lane], wb1 = sB[1][lane];
            const float4 wb2 = sB[2][lane], wb3 = sB[3][lane];
            const float4 wb4 = sB[4][lane], wb5 = sB[5][lane];
            const float4 wb6 = sB[6][lane], wb7 = sB[7][lane];
            DOT4(a1A, wb0, hv0); DOT4(a1B, wb1, hv1);
            DOT4(a1C, wb2, hv2); DOT4(a1D, wb3, hv3);
            DOT4(a1A, wb4, hv4); DOT4(a1B, wb5, hv5);
            DOT4(a1C, wb6, hv6); DOT4(a1D, wb7, hv7);
        }
        const float a0 = xa + (a0A + a0B) + (a0C + a0D);
        const float a1 = xb + (a1A + a1B) + (a1C + a1D);
        const float g0 = act_f(a0, SIG_CM, 1.0f, 0.0f);  // i (l<32) / f (l>=32)
        const float g1 = act_f(a1, cm1b, ka1b, kb1b);    // g (l<32) / o (l>=32)
        const float f_ = __shfl_xor(g0, 32);
        const float o_ = __shfl_xor(g1, 32);
        c1 = fmaf(f_, c1, g0 * g1);
        const float h1new = o_ * tanh_fast(c1);

        // ===== fused L2(i-1) [lanes 0-31] / L3(i-2) [lanes 32-63] =====
        float s0 = 0.f, s1 = 0.f, s2 = 0.f, s3 = 0.f;
        FMA4(s0, w23, hv0, 0);  FMA4(s0, w23, hv1, 4);  FMA4(s0, w23, hv2, 8);
        FMA4(s1, w23, hv3, 12); FMA4(s1, w23, hv4, 16); FMA4(s1, w23, hv5, 20);
        FMA4(s2, w23, hv6, 24); FMA4(s2, w23, hv7, 28); FMA4(s2, w23, u0, 32);
        FMA4(s3, w23, u1, 36);  FMA4(s3, w23, u2, 40);  FMA4(s3, w23, u3, 44);
        const float a23 = bias23 + (s0 + s1) + (s2 + s3);
        const float rv = act_f(a23, cm23, ka23, kb23);
        const float gi = __shfl(rv, gbase);
        const float gf = __shfl(rv, gbase + 8);
        const float gg = __shfl(rv, gbase + 16);
        const float go = __shfl(rv, gbase + 24);
        const bool on = (i >= thresh);
        c23 = on ? fmaf(gf, c23, gi * gg) : 0.0f;
        const float hnew = go * tanh_fast(c23);  // h2new (lower) / h3new (upper)

        // out(t3 = i-2) from lanes 32-39
        if (i >= 2 && (lane & 56) == 32)
            out[(i - 2) * (B * H3) + b * H3 + (lane & 7)] = hnew * m3;

        // ---- writes at bottom ----
        if (lane < H1) sh_h1[par][lane] = h1new;
        if ((lane & 24) == 0)  // lanes 0-7 -> h2, lanes 32-39 -> h3
            sh23[par][(lane & 7) | ((lane & 32) >> 2)] = hnew;
    };

    for (int i = 0; i < T + 2; i += 2) {
        float tA0, tB0, tA1, tB1;
        step(i,     0, xA0, xB0, tA0, tB0);
        step(i + 1, 1, xA1, xB1, tA1, tB1);
        xA0 = xA2; xB0 = xB2; xA1 = xA3; xB1 = xB3;
        xA2 = tA0; xB2 = tB0; xA3 = tA1; xB3 = tB1;
    }
}

// ---------------------------------------------------------------------------
// Fallback (R3 structure, self-contained): used iff ws_size too small.
// ---------------------------------------------------------------------------
__global__ __launch_bounds__(64, 1) void lstm3_fallback_kernel(
    const float* __restrict__ x,
    const float* __restrict__ Wih1, const float* __restrict__ Whh1,
    const float* __restrict__ bih1, const float* __restrict__ bhh1,
    const float* __restrict__ Wih2, const float* __restrict__ Whh2,
    const float* __restrict__ bih2, const float* __restrict__ bhh2,
    const float* __restrict__ Wih3, const float* __restrict__ Whh3,
    const float* __restrict__ bih3, const float* __restrict__ bhh3,
    const float* __restrict__ mask1, const float* __restrict__ mask2,
    const float* __restrict__ mask3,
    float* __restrict__ out)
{
    const int lane = threadIdx.x;
    const int b = blockIdx.x;

    __shared__ __align__(16) float sh_x[2][F];
    __shared__ __align__(16) float sh_h1[H1];
    __shared__ __align__(16) float sh_h2[H2];
    __shared__ __align__(16) float sh_h3[H3];

    const int r0 = lane, r1 = lane + 64;
    float wi1a[F], wh1a[H1], wi1b[F], wh1b[H1];
#pragma unroll
    for (int k = 0; k < F; ++k) { wi1a[k] = Wih1[r0 * F + k]; wi1b[k] = Wih1[r1 * F + k]; }
#pragma unroll
    for (int k = 0; k < H1; ++k) { wh1a[k] = Whh1[r0 * H1 + k]; wh1b[k] = Whh1[r1 * H1 + k]; }
    const float bias0 = bih1[r0] + bhh1[r0];
    const float bias1 = bih1[r1] + bhh1[r1];
    const float cm1b = (lane < 32) ? 2.0f * SIG_CM : SIG_CM;
    const float ka1b = (lane < 32) ? 2.0f : 1.0f;
    const float kb1b = (lane < 32) ? -1.0f : 0.0f;

    const int r2 = lane & 31;
    float wi2[H1], wh2[H2];
#pragma unroll
    for (int k = 0; k < H1; ++k) wi2[k] = Wih2[r2 * H1 + k] * mask1[b * H1 + k];
#pragma unroll
    for (int k = 0; k < H2; ++k) wh2[k] = Whh2[r2 * H2 + k];
    const float bias2 = bih2[r2] + bhh2[r2];
    const int sec2 = r2 >> 3;
    const float cm2 = (sec2 == 2) ? 2.0f * SIG_CM : SIG_CM;
    const float ka2 = (sec2 == 2) ? 2.0f : 1.0f;
    const float kb2 = (sec2 == 2) ? -1.0f : 0.0f;

    float wi3[H2], wh3[H3];
#pragma unroll
    for (int k = 0; k < H2; ++k) wi3[k] = Wih3[r2 * H2 + k] * mask2[b * H2 + k];
#pragma unroll
    for (int k = 0; k < H3; ++k) wh3[k] = Whh3[r2 * H3 + k];
    const float bias3 = bih3[r2] + bhh3[r2];

    const float m3 = mask3[b * H3 + (lane & 7)];

    float c1 = 0.f, c2 = 0.f, c3 = 0.f;
    if (lane < F) sh_x[0][lane] = x[b * F + lane];
    if (lane < H1) sh_h1[lane] = 0.f;
    if (lane < H2) sh_h2[lane] = 0.f;
    if (lane < H3) sh_h3[lane] = 0.f;
    WAVE_SYNC();

    const int j = lane & 7;

    for (int t = 0; t < T; ++t) {
        const int cur = t & 1, nxt = cur ^ 1;
        float xnext = 0.f;
        {
            const int tn = (t + 1 < T) ? (t + 1) : t;
            if (lane < F) xnext = x[tn * (B * F) + b * F + lane];
        }
        float a0x = 0.f, a0h = 0.f, a1x = 0.f, a1h = 0.f;
        {
            const float4* xp = (const float4*)sh_x[cur];
            const float4* hp = (const float4*)sh_h1;
#pragma unroll
            for (int q = 0; q < 8; ++q) {
                float4 xv = xp[q], hv = hp[q];
                FMA4(a0x, wi1a, xv, 4 * q);
                FMA4(a0h, wh1a, hv, 4 * q);
                FMA4(a1x, wi1b, xv, 4 * q);
                FMA4(a1h, wh1b, hv, 4 * q);
            }
        }
        const float a0 = bias0 + a0x + a0h;
        const float a1 = bias1 + a1x + a1h;
        const float g0 = act_f(a0, SIG_CM, 1.0f, 0.0f);
        const float g1 = act_f(a1, cm1b, ka1b, kb1b);
        const float f_ = __shfl_xor(g0, 32);
        const float o_ = __shfl_xor(g1, 32);
        c1 = fmaf(f_, c1, g0 * g1);
        const float h1 = o_ * tanh_fast(c1);

        WAVE_SYNC();
        if (lane < H1) sh_h1[lane] = h1;
        if (lane < F) sh_x[nxt][lane] = xnext;
        WAVE_SYNC();

        float a2x = 0.f, a2h = 0.f;
        {
            const float4* hp = (const float4*)sh_h1;
#pragma unroll
            for (int q = 0; q < 8; ++q) { float4 hv = hp[q]; FMA4(a2x, wi2, hv, 4 * q); }
            const float4* h2p = (const float4*)sh_h2;
            float4 v0 = h2p[0], v1 = h2p[1];
            FMA4(a2h, wh2, v0, 0);
            FMA4(a2h, wh2, v1, 4);
        }
        const float a2 = bias2 + a2x + a2h;
        const float r2v = act_f(a2, cm2, ka2, kb2);
        const float i2 = __shfl(r2v, j);
        const float f2 = __shfl(r2v, j + 8);
        const float g2 = __shfl(r2v, j + 16);
        const float o2 = __shfl(r2v, j + 24);
        c2 = fmaf(f2, c2, i2 * g2);
        const float h2 = o2 * tanh_fast(c2);

        WAVE_SYNC();
        if (lane < H2) sh_h2[lane] = h2;
        WAVE_SYNC();

        float a3x = 0.f, a3h = 0.f;
        {
            const float4* h2p = (const float4*)sh_h2;
            const float4* h3p = (const float4*)sh_h3;
            float4 u0 = h2p[0], u1 = h2p[1];
            FMA4(a3x, wi3, u0, 0);
            FMA4(a3x, wi3, u1, 4);
            float4 w0 = h3p[0], w1 = h3p[1];
            FMA4(a3h, wh3, w0, 0);
            FMA4(a3h, wh3, w1, 4);
        }
        const float a3 = bias3 + a3x + a3h;
        const float r3v = act_f(a3, cm2, ka2, kb2);
        const float i3 = __shfl(r3v, j);
        const float f3 = __shfl(r3v, j + 8);
        const float g3 = __shfl(r3v, j + 16);
        const float o3 = __shfl(r3v, j + 24);
        c3 = fmaf(f3, c3, i3 * g3);
        const float h3 = o3 * tanh_fast(c3);

        if (lane < H3) out[t * (B * H3) + b * H3 + lane] = h3 * m3;

        WAVE_SYNC();
        if (lane < H3) sh_h3[lane] = h3;
        WAVE_SYNC();
    }
}

extern "C" void kernel_launch(void* const* d_in, const int* in_sizes, int n_in,
                              void* d_out, int out_size, void* d_ws, size_t ws_size,
                              hipStream_t stream) {
    (void)in_sizes; (void)n_in; (void)out_size;
    const float* x     = (const float*)d_in[0];
    const float* Wih1  = (const float*)d_in[1];
    const float* Whh1  = (const float*)d_in[2];
    const float* bih1  = (const float*)d_in[3];
    const float* bhh1  = (const float*)d_in[4];
    const float* Wih2  = (const float*)d_in[5];
    const float* Whh2  = (const float*)d_in[6];
    const float* bih2  = (const float*)d_in[7];
    const float* bhh2  = (const float*)d_in[8];
    const float* Wih3  = (const float*)d_in[9];
    const float* Whh3  = (const float*)d_in[10];
    const float* bih3  = (const float*)d_in[11];
    const float* bhh3  = (const float*)d_in[12];
    const float* mask1 = (const float*)d_in[13];
    const float* mask2 = (const float*)d_in[14];
    const float* mask3 = (const float*)d_in[15];
    float* out = (float*)d_out;

    const size_t xg_bytes = (size_t)T * B * G1 * sizeof(float);  // 256 MB
    if (ws_size >= xg_bytes) {
        float* xg = (float*)d_ws;
        xg_kernel<<<dim3(T * B / GPB), dim3(128), 0, stream>>>(
            x, Wih1, bih1, bhh1, xg);
        lstm3_rec_kernel<<<dim3(B), dim3(64), 0, stream>>>(
            xg, Whh1, Wih2, Whh2, bih2, bhh2,
            Wih3, Whh3, bih3, bhh3, mask1, mask2, mask3, out);
    } else {
        lstm3_fallback_kernel<<<dim3(B), dim3(64), 0, stream>>>(
            x, Wih1, Whh1, bih1, bhh1, Wih2, Whh2, bih2, bhh2,
            Wih3, Whh3, bih3, bhh3, mask1, mask2, mask3, out);
    }
}

// Round 9
// 715.922 us; speedup vs baseline: 1.3149x; 1.1358x over previous
//
#include <hip/hip_runtime.h>

// 3-layer LSTM (T=1024,B=512,F=32,H1=32,H2=8,H3=8) + locked dropout.
//
// R9: WAVE SPECIALIZATION so ALL weights are genuinely register-resident.
// Evidence R5-R8: the allocator refuses >~50 weight floats/lane; every
// fallback pipe for per-step weight re-delivery costs ~1400 cyc/step
// (scratch vmem in R7, conflicted LDS b128 in R8: 459K SQ_LDS_BANK_CONFLICT).
// Fix: block = 192 threads (3 waves) per batch element.
//   waves 0-1: one L1 gate row per thread -> 32 weight floats/lane (fits).
//   wave 2   : fused L2/L3 half-wave rows -> 48 floats/lane (fits, R8-proven).
// Cross-wave h1 assembly via LDS + raw `s_waitcnt lgkmcnt(0); s_barrier`
// (NO vmcnt drain -> xg prefetch and out stores stay asynchronous).
// Output buffered in LDS ring, flushed coalesced every 64 steps.
// 6 waves/CU (vs 2) for issue overlap.

constexpr int T = 1024, B = 512, F = 32;
constexpr int H1 = 32, H2 = 8, H3 = 8;
constexpr int G1 = 4 * H1;  // 128 gate rows, layer 1

// LDS-only barrier: waits lgkmcnt(0) (own LDS ops complete) then s_barrier.
// Deliberately does NOT drain vmcnt -> global prefetch/stores stay in flight.
#define BAR() asm volatile("s_waitcnt lgkmcnt(0)\n\ts_barrier" ::: "memory")
#define WAVE_SYNC() asm volatile("" ::: "memory")
#define PIN(v) asm volatile("" : "+v"(v))

#if __has_builtin(__builtin_amdgcn_rcpf)
#define RCPF(x) __builtin_amdgcn_rcpf(x)
#else
#define RCPF(x) (1.0f / (x))
#endif
#if __has_builtin(__builtin_amdgcn_exp2f)
#define EXP2F(x) __builtin_amdgcn_exp2f(x)
#else
#define EXP2F(x) exp2f(x)
#endif

#define SIG_CM (-1.4426950408889634f)

__device__ __forceinline__ float act_f(float v, float cm, float ka, float kb) {
    return fmaf(ka, RCPF(1.0f + EXP2F(v * cm)), kb);
}
__device__ __forceinline__ float tanh_fast(float v) {
    return fmaf(2.0f, RCPF(1.0f + EXP2F(v * (2.0f * SIG_CM))), -1.0f);
}

// macro params avoid float4 member names x/y/z/w (R1 lesson)
#define FMA4(ACC, WARR, VEC, BASE)                                             \
    ACC = fmaf(WARR[(BASE) + 0], VEC.x, ACC);                                  \
    ACC = fmaf(WARR[(BASE) + 1], VEC.y, ACC);                                  \
    ACC = fmaf(WARR[(BASE) + 2], VEC.z, ACC);                                  \
    ACC = fmaf(WARR[(BASE) + 3], VEC.w, ACC);

#define DOT4(ACC, WV, VV)                                                      \
    ACC = fmaf(WV.x, VV.x, ACC);                                               \
    ACC = fmaf(WV.y, VV.y, ACC);                                               \
    ACC = fmaf(WV.z, VV.z, ACC);                                               \
    ACC = fmaf(WV.w, VV.w, ACC);

// ---------------------------------------------------------------------------
// Kernel A: xg[(t*B+b)*128 + r] = dot(Wih1[r], x[t][b]) + bih1[r] + bhh1[r]
// 128 threads (= rows), GPB=32 pairs/block (16384 blocks -> high occupancy),
// 2-pair ILP in the inner loop to break the FMA dependency chain.
// ---------------------------------------------------------------------------
constexpr int GPB = 32;  // (t,b) pairs per block

__global__ __launch_bounds__(128) void xg_kernel(
    const float* __restrict__ x, const float* __restrict__ Wih1,
    const float* __restrict__ bih1, const float* __restrict__ bhh1,
    float* __restrict__ xg)
{
    __shared__ __align__(16) float4 sx4[GPB * 8];  // 4KB

    const int tid = threadIdx.x;       // gate row 0..127
    const int pair0 = blockIdx.x * GPB;

    float4 w4[8];
#pragma unroll
    for (int q = 0; q < 8; ++q) w4[q] = ((const float4*)Wih1)[tid * 8 + q];
    const float bias = bih1[tid] + bhh1[tid];

#pragma unroll
    for (int d = tid; d < GPB * 8; d += 128)
        sx4[d] = ((const float4*)x)[(size_t)pair0 * 8 + d];  // coalesced
    __syncthreads();

    for (int p = 0; p < GPB; p += 2) {
        float acc0 = bias, acc1 = bias;
#pragma unroll
        for (int q = 0; q < 8; ++q) {
            const float4 xv0 = sx4[p * 8 + q];       // broadcast
            const float4 xv1 = sx4[p * 8 + 8 + q];   // broadcast
            DOT4(acc0, w4[q], xv0);
            DOT4(acc1, w4[q], xv1);
        }
        xg[(size_t)(pair0 + p) * G1 + tid] = acc0;       // 512B coalesced
        xg[(size_t)(pair0 + p + 1) * G1 + tid] = acc1;
    }
}

// ---------------------------------------------------------------------------
// Kernel B: wave-specialized skewed scan. Block=192 threads per batch elem.
//   waves 0-1 (tid 0..127): L1 gate row tid (32 reg weights).
//   wave 2   (tid 128..191): fused L2(i-1)/L3(i-2) (48 reg weights).
// Per step: phaseA (gates + L2/L3) -> BAR -> [flush] -> phaseB (c1/h1) -> BAR.
// ---------------------------------------------------------------------------
__global__ __launch_bounds__(192, 1) void lstm3_rec_kernel(
    const float* __restrict__ xg,
    const float* __restrict__ Whh1,
    const float* __restrict__ Wih2, const float* __restrict__ Whh2,
    const float* __restrict__ bih2, const float* __restrict__ bhh2,
    const float* __restrict__ Wih3, const float* __restrict__ Whh3,
    const float* __restrict__ bih3, const float* __restrict__ bhh3,
    const float* __restrict__ mask1, const float* __restrict__ mask2,
    const float* __restrict__ mask3,
    float* __restrict__ out)
{
    const int tid = threadIdx.x;
    const int lane = tid & 63;
    const int wid = tid >> 6;
    const int b = blockIdx.x;

    __shared__ __align__(16) float sh_gates[G1];        // raw L1 gates
    __shared__ __align__(16) float sh_h1[2][H1];        // h1 parity buffers
    __shared__ __align__(16) float sh23[2][16];         // [par][0..7]=h2,[8..15]=h3
    __shared__ __align__(16) float sh_ob[2][64 * H3];   // out ring (2x64 steps)

    // ---------------- per-role weights (register-resident) ----------------
    float wreg[48];
    float cmX, kaX, kbX, biasX = 0.f, m3 = 0.f;
    int thresh = 0, gbase = 0;

    if (wid < 2) {
        // L1 gate row tid: 32 Whh1 weights (bias folded into xg)
#pragma unroll
        for (int k = 0; k < H1; ++k) wreg[k] = Whh1[tid * H1 + k];
#pragma unroll
        for (int k = H1; k < 48; ++k) wreg[k] = 0.f;
        const int sec = tid >> 5;  // 0=i 1=f 2=g 3=o
        cmX = (sec == 2) ? 2.0f * SIG_CM : SIG_CM;
        kaX = (sec == 2) ? 2.0f : 1.0f;
        kbX = (sec == 2) ? -1.0f : 0.0f;
    } else {
        // fused L2/L3: 48-term dot over [h1(32) | h2(8) | h3(8)]
        const int r = lane & 31;
        const bool lower = (lane < 32);
        if (lower) {  // L2 gate row r
#pragma unroll
            for (int k = 0; k < H1; ++k) wreg[k] = Wih2[r * H1 + k] * mask1[b * H1 + k];
#pragma unroll
            for (int k = 0; k < H2; ++k) wreg[32 + k] = Whh2[r * H2 + k];
#pragma unroll
            for (int k = 0; k < H3; ++k) wreg[40 + k] = 0.0f;
            biasX = bih2[r] + bhh2[r];
        } else {      // L3 gate row r
#pragma unroll
            for (int k = 0; k < H1; ++k) wreg[k] = 0.0f;
#pragma unroll
            for (int k = 0; k < H2; ++k) wreg[32 + k] = Wih3[r * H2 + k] * mask2[b * H2 + k];
#pragma unroll
            for (int k = 0; k < H3; ++k) wreg[40 + k] = Whh3[r * H3 + k];
            biasX = bih3[r] + bhh3[r];
        }
        const int sec = r >> 3;
        cmX = (sec == 2) ? 2.0f * SIG_CM : SIG_CM;
        kaX = (sec == 2) ? 2.0f : 1.0f;
        kbX = (sec == 2) ? -1.0f : 0.0f;
        m3 = mask3[b * H3 + (lane & 7)];
        thresh = lower ? 1 : 2;
        gbase = (lane & 32) + (lane & 7);
    }
#pragma unroll
    for (int k = 0; k < 32; ++k) PIN(wreg[k]);
    if (wid == 2) {
#pragma unroll
        for (int k = 32; k < 48; ++k) PIN(wreg[k]);
    }
    PIN(cmX); PIN(kaX); PIN(kbX); PIN(biasX); PIN(m3);

    // ---------------- state init ----------------
    float c1 = 0.f, c23 = 0.f;
    if (tid < H1) { sh_h1[0][tid] = 0.f; sh_h1[1][tid] = 0.f; }
    if (tid >= 32 && tid < 48) { sh23[0][tid - 32] = 0.f; sh23[1][tid - 32] = 0.f; }
    BAR();

    // xg prefetch ring (waves 0/1 only), distance 4 — the only in-loop vmem
    const int xoff = b * G1 + tid;
    float x0 = 0.f, x1 = 0.f, x2 = 0.f, x3 = 0.f;
    if (wid < 2) {
        x0 = xg[(size_t)0 * 65536 + xoff];
        x1 = xg[(size_t)1 * 65536 + xoff];
        x2 = xg[(size_t)2 * 65536 + xoff];
        x3 = xg[(size_t)3 * 65536 + xoff];
    }

    auto step = [&](int i, int par, float xcur, float& xnew) {
        // ================= phase A =================
        if (wid < 2) {
            {   // prefetch xg(i+4), clamped
                int tp = i + 4; tp = (tp < T) ? tp : (T - 1);
                xnew = xg[(size_t)tp * 65536 + xoff];
            }
            const float4* h1p = (const float4*)sh_h1[par ^ 1];
            float aA = 0.f, aB = 0.f, aC = 0.f, aD = 0.f;
            {
                const float4 v0 = h1p[0], v1 = h1p[1], v2 = h1p[2], v3 = h1p[3];
                FMA4(aA, wreg, v0, 0);  FMA4(aB, wreg, v1, 4);
                FMA4(aC, wreg, v2, 8);  FMA4(aD, wreg, v3, 12);
            }
            {
                const float4 v4 = h1p[4], v5 = h1p[5], v6 = h1p[6], v7 = h1p[7];
                FMA4(aA, wreg, v4, 16); FMA4(aB, wreg, v5, 20);
                FMA4(aC, wreg, v6, 24); FMA4(aD, wreg, v7, 28);
            }
            const float a = xcur + (aA + aB) + (aC + aD);
            sh_gates[tid] = act_f(a, cmX, kaX, kbX);
        } else {
            xnew = 0.f;
            const float4* h1p = (const float4*)sh_h1[par ^ 1];
            const float4* up = (const float4*)sh23[par ^ 1];
            float s0 = 0.f, s1 = 0.f, s2 = 0.f, s3 = 0.f;
            {
                const float4 v0 = h1p[0], v1 = h1p[1], v2 = h1p[2];
                FMA4(s0, wreg, v0, 0);  FMA4(s0, wreg, v1, 4);  FMA4(s0, wreg, v2, 8);
            }
            {
                const float4 v3 = h1p[3], v4 = h1p[4], v5 = h1p[5];
                FMA4(s1, wreg, v3, 12); FMA4(s1, wreg, v4, 16); FMA4(s1, wreg, v5, 20);
            }
            {
                const float4 v6 = h1p[6], v7 = h1p[7], u0 = up[0];
                FMA4(s2, wreg, v6, 24); FMA4(s2, wreg, v7, 28); FMA4(s2, wreg, u0, 32);
            }
            {
                const float4 u1 = up[1], u2 = up[2], u3 = up[3];
                FMA4(s3, wreg, u1, 36); FMA4(s3, wreg, u2, 40); FMA4(s3, wreg, u3, 44);
            }
            const float a23 = biasX + (s0 + s1) + (s2 + s3);
            const float rv = act_f(a23, cmX, kaX, kbX);
            const float gi = __shfl(rv, gbase);
            const float gf = __shfl(rv, gbase + 8);
            const float gg = __shfl(rv, gbase + 16);
            const float go = __shfl(rv, gbase + 24);
            c23 = (i >= thresh) ? fmaf(gf, c23, gi * gg) : 0.0f;
            const float hnew = go * tanh_fast(c23);  // h2(i-1) / h3(i-2)
            if (i >= 2 && (lane & 56) == 32)         // lanes 32-39: out(i-2)
                sh_ob[((i - 2) >> 6) & 1][((i - 2) & 63) * H3 + (lane & 7)] = hnew * m3;
            if ((lane & 24) == 0)                    // lanes 0-7 h2, 32-39 h3
                sh23[par][(lane & 7) | ((lane & 32) >> 2)] = hnew;
        }
        BAR();  // lgkmcnt only — vmem (prefetch/stores) stays in flight

        // ======== periodic coalesced out flush (64 steps buffered) ========
        if (i >= 65 && (i & 63) == 1) {
            const int t0 = i - 65;
            if (tid < 128) {
                const int s = tid >> 1, half = (tid & 1) * 4;
                const float4 v = *(const float4*)&sh_ob[(t0 >> 6) & 1][s * H3 + half];
                *(float4*)&out[(size_t)(t0 + s) * (B * H3) + b * H3 + half] = v;
            }
        }

        // ================= phase B: c1/h1 update =================
        if (tid < 32) {
            const float gi = sh_gates[tid];
            const float gf = sh_gates[tid + 32];
            const float gg = sh_gates[tid + 64];
            const float go = sh_gates[tid + 96];
            c1 = fmaf(gf, c1, gi * gg);
            sh_h1[par][tid] = go * tanh_fast(c1);
        }
        BAR();
    };

    for (int i = 0; i <= T; i += 2) {   // runs steps 0..T+1 (skew drain)
        float n0 = 0.f, n1 = 0.f;
        step(i, 0, x0, n0);
        step(i + 1, 1, x1, n1);
        x0 = x2; x1 = x3; x2 = n0; x3 = n1;
    }
}

// ---------------------------------------------------------------------------
// Fallback (R3 structure, self-contained): used iff ws_size too small.
// ---------------------------------------------------------------------------
__global__ __launch_bounds__(64, 1) void lstm3_fallback_kernel(
    const float* __restrict__ x,
    const float* __restrict__ Wih1, const float* __restrict__ Whh1,
    const float* __restrict__ bih1, const float* __restrict__ bhh1,
    const float* __restrict__ Wih2, const float* __restrict__ Whh2,
    const float* __restrict__ bih2, const float* __restrict__ bhh2,
    const float* __restrict__ Wih3, const float* __restrict__ Whh3,
    const float* __restrict__ bih3, const float* __restrict__ bhh3,
    const float* __restrict__ mask1, const float* __restrict__ mask2,
    const float* __restrict__ mask3,
    float* __restrict__ out)
{
    const int lane = threadIdx.x;
    const int b = blockIdx.x;

    __shared__ __align__(16) float sh_x[2][F];
    __shared__ __align__(16) float sh_h1[H1];
    __shared__ __align__(16) float sh_h2[H2];
    __shared__ __align__(16) float sh_h3[H3];

    const int r0 = lane, r1 = lane + 64;
    float wi1a[F], wh1a[H1], wi1b[F], wh1b[H1];
#pragma unroll
    for (int k = 0; k < F; ++k) { wi1a[k] = Wih1[r0 * F + k]; wi1b[k] = Wih1[r1 * F + k]; }
#pragma unroll
    for (int k = 0; k < H1; ++k) { wh1a[k] = Whh1[r0 * H1 + k]; wh1b[k] = Whh1[r1 * H1 + k]; }
    const float bias0 = bih1[r0] + bhh1[r0];
    const float bias1 = bih1[r1] + bhh1[r1];
    const float cm1b = (lane < 32) ? 2.0f * SIG_CM : SIG_CM;
    const float ka1b = (lane < 32) ? 2.0f : 1.0f;
    const float kb1b = (lane < 32) ? -1.0f : 0.0f;

    const int r2 = lane & 31;
    float wi2[H1], wh2[H2];
#pragma unroll
    for (int k = 0; k < H1; ++k) wi2[k] = Wih2[r2 * H1 + k] * mask1[b * H1 + k];
#pragma unroll
    for (int k = 0; k < H2; ++k) wh2[k] = Whh2[r2 * H2 + k];
    const float bias2 = bih2[r2] + bhh2[r2];
    const int sec2 = r2 >> 3;
    const float cm2 = (sec2 == 2) ? 2.0f * SIG_CM : SIG_CM;
    const float ka2 = (sec2 == 2) ? 2.0f : 1.0f;
    const float kb2 = (sec2 == 2) ? -1.0f : 0.0f;

    float wi3[H2], wh3[H3];
#pragma unroll
    for (int k = 0; k < H2; ++k) wi3[k] = Wih3[r2 * H2 + k] * mask2[b * H2 + k];
#pragma unroll
    for (int k = 0; k < H3; ++k) wh3[k] = Whh3[r2 * H3 + k];
    const float bias3 = bih3[r2] + bhh3[r2];

    const float m3 = mask3[b * H3 + (lane & 7)];

    float c1 = 0.f, c2 = 0.f, c3 = 0.f;
    if (lane < F) sh_x[0][lane] = x[b * F + lane];
    if (lane < H1) sh_h1[lane] = 0.f;
    if (lane < H2) sh_h2[lane] = 0.f;
    if (lane < H3) sh_h3[lane] = 0.f;
    WAVE_SYNC();

    const int j = lane & 7;

    for (int t = 0; t < T; ++t) {
        const int cur = t & 1, nxt = cur ^ 1;
        float xnext = 0.f;
        {
            const int tn = (t + 1 < T) ? (t + 1) : t;
            if (lane < F) xnext = x[tn * (B * F) + b * F + lane];
        }
        float a0x = 0.f, a0h = 0.f, a1x = 0.f, a1h = 0.f;
        {
            const float4* xp = (const float4*)sh_x[cur];
            const float4* hp = (const float4*)sh_h1;
#pragma unroll
            for (int q = 0; q < 8; ++q) {
                float4 xv = xp[q], hv = hp[q];
                FMA4(a0x, wi1a, xv, 4 * q);
                FMA4(a0h, wh1a, hv, 4 * q);
                FMA4(a1x, wi1b, xv, 4 * q);
                FMA4(a1h, wh1b, hv, 4 * q);
            }
        }
        const float a0 = bias0 + a0x + a0h;
        const float a1 = bias1 + a1x + a1h;
        const float g0 = act_f(a0, SIG_CM, 1.0f, 0.0f);
        const float g1 = act_f(a1, cm1b, ka1b, kb1b);
        const float f_ = __shfl_xor(g0, 32);
        const float o_ = __shfl_xor(g1, 32);
        c1 = fmaf(f_, c1, g0 * g1);
        const float h1 = o_ * tanh_fast(c1);

        WAVE_SYNC();
        if (lane < H1) sh_h1[lane] = h1;
        if (lane < F) sh_x[nxt][lane] = xnext;
        WAVE_SYNC();

        float a2x = 0.f, a2h = 0.f;
        {
            const float4* hp = (const float4*)sh_h1;
#pragma unroll
            for (int q = 0; q < 8; ++q) { float4 hv = hp[q]; FMA4(a2x, wi2, hv, 4 * q); }
            const float4* h2p = (const float4*)sh_h2;
            float4 v0 = h2p[0], v1 = h2p[1];
            FMA4(a2h, wh2, v0, 0);
            FMA4(a2h, wh2, v1, 4);
        }
        const float a2 = bias2 + a2x + a2h;
        const float r2v = act_f(a2, cm2, ka2, kb2);
        const float i2 = __shfl(r2v, j);
        const float f2 = __shfl(r2v, j + 8);
        const float g2 = __shfl(r2v, j + 16);
        const float o2 = __shfl(r2v, j + 24);
        c2 = fmaf(f2, c2, i2 * g2);
        const float h2 = o2 * tanh_fast(c2);

        WAVE_SYNC();
        if (lane < H2) sh_h2[lane] = h2;
        WAVE_SYNC();

        float a3x = 0.f, a3h = 0.f;
        {
            const float4* h2p = (const float4*)sh_h2;
            const float4* h3p = (const float4*)sh_h3;
            float4 u0 = h2p[0], u1 = h2p[1];
            FMA4(a3x, wi3, u0, 0);
            FMA4(a3x, wi3, u1, 4);
            float4 w0 = h3p[0], w1 = h3p[1];
            FMA4(a3h, wh3, w0, 0);
            FMA4(a3h, wh3, w1, 4);
        }
        const float a3 = bias3 + a3x + a3h;
        const float r3v = act_f(a3, cm2, ka2, kb2);
        const float i3 = __shfl(r3v, j);
        const float f3 = __shfl(r3v, j + 8);
        const float g3 = __shfl(r3v, j + 16);
        const float o3 = __shfl(r3v, j + 24);
        c3 = fmaf(f3, c3, i3 * g3);
        const float h3 = o3 * tanh_fast(c3);

        if (lane < H3) out[t * (B * H3) + b * H3 + lane] = h3 * m3;

        WAVE_SYNC();
        if (lane < H3) sh_h3[lane] = h3;
        WAVE_SYNC();
    }
}

extern "C" void kernel_launch(void* const* d_in, const int* in_sizes, int n_in,
                              void* d_out, int out_size, void* d_ws, size_t ws_size,
                              hipStream_t stream) {
    (void)in_sizes; (void)n_in; (void)out_size;
    const float* x     = (const float*)d_in[0];
    const float* Wih1  = (const float*)d_in[1];
    const float* Whh1  = (const float*)d_in[2];
    const float* bih1  = (const float*)d_in[3];
    const float* bhh1  = (const float*)d_in[4];
    const float* Wih2  = (const float*)d_in[5];
    const float* Whh2  = (const float*)d_in[6];
    const float* bih2  = (const float*)d_in[7];
    const float* bhh2  = (const float*)d_in[8];
    const float* Wih3  = (const float*)d_in[9];
    const float* Whh3  = (const float*)d_in[10];
    const float* bih3  = (const float*)d_in[11];
    const float* bhh3  = (const float*)d_in[12];
    const float* mask1 = (const float*)d_in[13];
    const float* mask2 = (const float*)d_in[14];
    const float* mask3 = (const float*)d_in[15];
    float* out = (float*)d_out;

    const size_t xg_bytes = (size_t)T * B * G1 * sizeof(float);  // 256 MB
    if (ws_size >= xg_bytes) {
        float* xg = (float*)d_ws;
        xg_kernel<<<dim3(T * B / GPB), dim3(128), 0, stream>>>(
            x, Wih1, bih1, bhh1, xg);
        lstm3_rec_kernel<<<dim3(B), dim3(192), 0, stream>>>(
            xg, Whh1, Wih2, Whh2, bih2, bhh2,
            Wih3, Whh3, bih3, bhh3, mask1, mask2, mask3, out);
    } else {
        lstm3_fallback_kernel<<<dim3(B), dim3(64), 0, stream>>>(
            x, Wih1, Whh1, bih1, bhh1, Wih2, Whh2, bih2, bhh2,
            Wih3, Whh3, bih3, bhh3, mask1, mask2, mask3, out);
    }
}

// Round 10
// 699.288 us; speedup vs baseline: 1.3461x; 1.0238x over previous
//
#include <hip/hip_runtime.h>

// 3-layer LSTM (T=1024,B=512,F=32,H1=32,H2=8,H3=8) + locked dropout.
//
// R10: ONE barrier per step via redundant h1-update + private per-wave h1.
// R9 (548us rec) had 2 barriers/step and a wave0-only phase B on the critical
// path. Now: all 3 waves redundantly compute the h1 update (c1 kept per-wave)
// and write their OWN LDS copy of h1 -> h1 write->read is intra-wave in-order
// (no barrier); only the gates handoff (waves0-1 -> all) needs the barrier.
// Gates stored j-major so phase B reads them as one ds_read_b128.
// Gates double-buffered by parity: max wave skew through 1 barrier/step is
// <2 steps -> no WAR race. Out staged in LDS ring, flushed coalesced / 64
// steps (vmem never on the barrier path: BAR waits lgkmcnt only).
// xg pre-pass: 4-pair ILP (4 independent FMA chains) -> issue-bound.

constexpr int T = 1024, B = 512, F = 32;
constexpr int H1 = 32, H2 = 8, H3 = 8;
constexpr int G1 = 4 * H1;  // 128 gate rows, layer 1

// LDS-only barrier: no vmcnt drain (prefetch/stores stay in flight).
#define BAR() asm volatile("s_waitcnt lgkmcnt(0)\n\ts_barrier" ::: "memory")
#define WAVE_SYNC() asm volatile("" ::: "memory")
#define PIN(v) asm volatile("" : "+v"(v))

#if __has_builtin(__builtin_amdgcn_rcpf)
#define RCPF(x) __builtin_amdgcn_rcpf(x)
#else
#define RCPF(x) (1.0f / (x))
#endif
#if __has_builtin(__builtin_amdgcn_exp2f)
#define EXP2F(x) __builtin_amdgcn_exp2f(x)
#else
#define EXP2F(x) exp2f(x)
#endif

#define SIG_CM (-1.4426950408889634f)

__device__ __forceinline__ float act_f(float v, float cm, float ka, float kb) {
    return fmaf(ka, RCPF(1.0f + EXP2F(v * cm)), kb);
}
__device__ __forceinline__ float tanh_fast(float v) {
    return fmaf(2.0f, RCPF(1.0f + EXP2F(v * (2.0f * SIG_CM))), -1.0f);
}

// macro params avoid float4 member names x/y/z/w (R1 lesson)
#define FMA4(ACC, WARR, VEC, BASE)                                             \
    ACC = fmaf(WARR[(BASE) + 0], VEC.x, ACC);                                  \
    ACC = fmaf(WARR[(BASE) + 1], VEC.y, ACC);                                  \
    ACC = fmaf(WARR[(BASE) + 2], VEC.z, ACC);                                  \
    ACC = fmaf(WARR[(BASE) + 3], VEC.w, ACC);

#define DOT4(ACC, WV, VV)                                                      \
    ACC = fmaf(WV.x, VV.x, ACC);                                               \
    ACC = fmaf(WV.y, VV.y, ACC);                                               \
    ACC = fmaf(WV.z, VV.z, ACC);                                               \
    ACC = fmaf(WV.w, VV.w, ACC);

// ---------------------------------------------------------------------------
// Kernel A: xg[(t*B+b)*128 + r] = dot(Wih1[r], x[t][b]) + bih1[r] + bhh1[r]
// 128 thr (= rows), GPB=64 pairs/block, 4-pair ILP (independent FMA chains).
// ---------------------------------------------------------------------------
constexpr int GPB = 64;  // (t,b) pairs per block

__global__ __launch_bounds__(128) void xg_kernel(
    const float* __restrict__ x, const float* __restrict__ Wih1,
    const float* __restrict__ bih1, const float* __restrict__ bhh1,
    float* __restrict__ xg)
{
    __shared__ __align__(16) float4 sx4[GPB * 8];  // 8KB

    const int tid = threadIdx.x;       // gate row 0..127
    const int pair0 = blockIdx.x * GPB;

    float4 w4[8];
#pragma unroll
    for (int q = 0; q < 8; ++q) w4[q] = ((const float4*)Wih1)[tid * 8 + q];
    const float bias = bih1[tid] + bhh1[tid];

#pragma unroll
    for (int d = tid; d < GPB * 8; d += 128)
        sx4[d] = ((const float4*)x)[(size_t)pair0 * 8 + d];  // coalesced
    __syncthreads();

    for (int p = 0; p < GPB; p += 4) {
        float a0 = bias, a1 = bias, a2 = bias, a3 = bias;
#pragma unroll
        for (int q = 0; q < 8; ++q) {
            const float4 v0 = sx4[(p + 0) * 8 + q];   // broadcast reads
            const float4 v1 = sx4[(p + 1) * 8 + q];
            const float4 v2 = sx4[(p + 2) * 8 + q];
            const float4 v3 = sx4[(p + 3) * 8 + q];
            DOT4(a0, w4[q], v0);
            DOT4(a1, w4[q], v1);
            DOT4(a2, w4[q], v2);
            DOT4(a3, w4[q], v3);
        }
        xg[(size_t)(pair0 + p + 0) * G1 + tid] = a0;  // 512B coalesced each
        xg[(size_t)(pair0 + p + 1) * G1 + tid] = a1;
        xg[(size_t)(pair0 + p + 2) * G1 + tid] = a2;
        xg[(size_t)(pair0 + p + 3) * G1 + tid] = a3;
    }
}

// ---------------------------------------------------------------------------
// Kernel B: wave-specialized skewed scan, ONE barrier per step.
//   waves 0-1 (tid 0..127): L1 gate row tid (32 reg weights).
//   wave 2   (tid 128..191): fused L2(i-1)/L3(i-2) (48 reg weights).
//   ALL waves: redundant c1/h1 update into their private sh_h1 copy.
// ---------------------------------------------------------------------------
__global__ __launch_bounds__(192, 1) void lstm3_rec_kernel(
    const float* __restrict__ xg,
    const float* __restrict__ Whh1,
    const float* __restrict__ Wih2, const float* __restrict__ Whh2,
    const float* __restrict__ bih2, const float* __restrict__ bhh2,
    const float* __restrict__ Wih3, const float* __restrict__ Whh3,
    const float* __restrict__ bih3, const float* __restrict__ bhh3,
    const float* __restrict__ mask1, const float* __restrict__ mask2,
    const float* __restrict__ mask3,
    float* __restrict__ out)
{
    const int tid = threadIdx.x;
    const int lane = tid & 63;
    const int wid = tid >> 6;
    const int b = blockIdx.x;

    __shared__ __align__(16) float sh_g[2][G1];         // j-major: [par][j*4+sec]
    __shared__ __align__(16) float sh_h1[3][2][H1];     // private per-wave h1
    __shared__ __align__(16) float sh23[2][16];         // wave2-only h2|h3
    __shared__ __align__(16) float sh_ob[2][64 * H3];   // out ring (2x64 steps)

    // ---------------- per-role weights (register-resident) ----------------
    float wreg[48];
    float cmX, kaX, kbX, biasX = 0.f, m3 = 0.f;
    int thresh = 0, gbase = 0;

    if (wid < 2) {
        // L1 gate row tid (bias folded into xg)
#pragma unroll
        for (int k = 0; k < H1; ++k) wreg[k] = Whh1[tid * H1 + k];
#pragma unroll
        for (int k = H1; k < 48; ++k) wreg[k] = 0.f;
        const int sec = tid >> 5;  // 0=i 1=f 2=g 3=o
        cmX = (sec == 2) ? 2.0f * SIG_CM : SIG_CM;
        kaX = (sec == 2) ? 2.0f : 1.0f;
        kbX = (sec == 2) ? -1.0f : 0.0f;
    } else {
        // fused L2/L3: 48-term dot over [h1(32) | h2(8) | h3(8)]
        const int r = lane & 31;
        const bool lower = (lane < 32);
        if (lower) {  // L2 gate row r
#pragma unroll
            for (int k = 0; k < H1; ++k) wreg[k] = Wih2[r * H1 + k] * mask1[b * H1 + k];
#pragma unroll
            for (int k = 0; k < H2; ++k) wreg[32 + k] = Whh2[r * H2 + k];
#pragma unroll
            for (int k = 0; k < H3; ++k) wreg[40 + k] = 0.0f;
            biasX = bih2[r] + bhh2[r];
        } else {      // L3 gate row r
#pragma unroll
            for (int k = 0; k < H1; ++k) wreg[k] = 0.0f;
#pragma unroll
            for (int k = 0; k < H2; ++k) wreg[32 + k] = Wih3[r * H2 + k] * mask2[b * H2 + k];
#pragma unroll
            for (int k = 0; k < H3; ++k) wreg[40 + k] = Whh3[r * H3 + k];
            biasX = bih3[r] + bhh3[r];
        }
        const int sec = r >> 3;
        cmX = (sec == 2) ? 2.0f * SIG_CM : SIG_CM;
        kaX = (sec == 2) ? 2.0f : 1.0f;
        kbX = (sec == 2) ? -1.0f : 0.0f;
        m3 = mask3[b * H3 + (lane & 7)];
        thresh = lower ? 1 : 2;
        gbase = (lane & 32) + (lane & 7);
    }
#pragma unroll
    for (int k = 0; k < 48; ++k) PIN(wreg[k]);
    PIN(cmX); PIN(kaX); PIN(kbX); PIN(biasX); PIN(m3);

    // ---------------- state init ----------------
    float c1 = 0.f, c23 = 0.f;
    if (lane < H1) { sh_h1[wid][0][lane] = 0.f; sh_h1[wid][1][lane] = 0.f; }
    if (wid == 2 && lane < 16) { sh23[0][lane] = 0.f; sh23[1][lane] = 0.f; }
    BAR();

    // xg prefetch ring (waves 0/1 only), distance 4 — the only in-loop vmem
    const int xoff = b * G1 + tid;
    float x0 = 0.f, x1 = 0.f, x2 = 0.f, x3 = 0.f;
    if (wid < 2) {
        x0 = xg[(size_t)0 * 65536 + xoff];
        x1 = xg[(size_t)1 * 65536 + xoff];
        x2 = xg[(size_t)2 * 65536 + xoff];
        x3 = xg[(size_t)3 * 65536 + xoff];
    }

    const int sec1 = tid >> 5;          // gate-slot for waves 0/1 writes
    const int jslot = (tid & 31) * 4;   // j-major base

    auto step = [&](int i, int par, float xcur, float& xnew) {
        // ================= phase 1 =================
        if (wid < 2) {
            {   // prefetch xg(i+4), clamped
                int tp = i + 4; tp = (tp < T) ? tp : (T - 1);
                xnew = xg[(size_t)tp * 65536 + xoff];
            }
            const float4* h1p = (const float4*)sh_h1[wid][par ^ 1];
            float aA = 0.f, aB = 0.f, aC = 0.f, aD = 0.f;
            {
                const float4 v0 = h1p[0], v1 = h1p[1], v2 = h1p[2], v3 = h1p[3];
                FMA4(aA, wreg, v0, 0);  FMA4(aB, wreg, v1, 4);
                FMA4(aC, wreg, v2, 8);  FMA4(aD, wreg, v3, 12);
            }
            {
                const float4 v4 = h1p[4], v5 = h1p[5], v6 = h1p[6], v7 = h1p[7];
                FMA4(aA, wreg, v4, 16); FMA4(aB, wreg, v5, 20);
                FMA4(aC, wreg, v6, 24); FMA4(aD, wreg, v7, 28);
            }
            const float a = xcur + (aA + aB) + (aC + aD);
            sh_g[par][jslot + sec1] = act_f(a, cmX, kaX, kbX);
        } else {
            xnew = 0.f;
            const float4* h1p = (const float4*)sh_h1[2][par ^ 1];
            const float4* up = (const float4*)sh23[par ^ 1];
            float s0 = 0.f, s1 = 0.f, s2 = 0.f, s3 = 0.f;
            {
                const float4 v0 = h1p[0], v1 = h1p[1], v2 = h1p[2];
                FMA4(s0, wreg, v0, 0);  FMA4(s0, wreg, v1, 4);  FMA4(s0, wreg, v2, 8);
            }
            {
                const float4 v3 = h1p[3], v4 = h1p[4], v5 = h1p[5];
                FMA4(s1, wreg, v3, 12); FMA4(s1, wreg, v4, 16); FMA4(s1, wreg, v5, 20);
            }
            {
                const float4 v6 = h1p[6], v7 = h1p[7], u0 = up[0];
                FMA4(s2, wreg, v6, 24); FMA4(s2, wreg, v7, 28); FMA4(s2, wreg, u0, 32);
            }
            {
                const float4 u1 = up[1], u2 = up[2], u3 = up[3];
                FMA4(s3, wreg, u1, 36); FMA4(s3, wreg, u2, 40); FMA4(s3, wreg, u3, 44);
            }
            const float a23 = biasX + (s0 + s1) + (s2 + s3);
            const float rv = act_f(a23, cmX, kaX, kbX);
            const float gi = __shfl(rv, gbase);
            const float gf = __shfl(rv, gbase + 8);
            const float gg = __shfl(rv, gbase + 16);
            const float go = __shfl(rv, gbase + 24);
            c23 = (i >= thresh) ? fmaf(gf, c23, gi * gg) : 0.0f;
            const float hnew = go * tanh_fast(c23);  // h2(i-1) / h3(i-2)
            if (i >= 2 && (lane & 56) == 32)         // lanes 32-39: out(i-2)
                sh_ob[((i - 2) >> 6) & 1][((i - 2) & 63) * H3 + (lane & 7)] = hnew * m3;
            if ((lane & 24) == 0)                    // lanes 0-7 h2, 32-39 h3
                sh23[par][(lane & 7) | ((lane & 32) >> 2)] = hnew;
        }
        BAR();  // the ONLY barrier: gates_i visible; lgkmcnt only

        // ======== periodic coalesced out flush (64 steps buffered) ========
        if (i >= 65 && (i & 63) == 1) {
            const int t0 = i - 65;
            if (tid < 128) {
                const int s = tid >> 1, half = (tid & 1) * 4;
                const float4 v = *(const float4*)&sh_ob[(t0 >> 6) & 1][s * H3 + half];
                *(float4*)&out[(size_t)(t0 + s) * (B * H3) + b * H3 + half] = v;
            }
        }

        // ====== phase 3: redundant c1/h1 update, ALL waves, own copy ======
        {
            const float4 g4 = *(const float4*)&sh_g[par][(lane & 31) * 4];
            c1 = fmaf(g4.y, c1, g4.x * g4.z);     // c1 = f*c1 + i*g
            const float h1new = g4.w * tanh_fast(c1);
            WAVE_SYNC();
            if (lane < H1) sh_h1[wid][par][lane] = h1new;
        }
        // no second barrier: next phase-1 reads the wave's OWN copy (in-order)
    };

    for (int i = 0; i <= T; i += 2) {   // steps 0..T+1 (skew drain)
        float n0 = 0.f, n1 = 0.f;
        step(i, 0, x0, n0);
        step(i + 1, 1, x1, n1);
        x0 = x2; x1 = x3; x2 = n0; x3 = n1;
    }
}

// ---------------------------------------------------------------------------
// Fallback (R3 structure, self-contained): used iff ws_size too small.
// ---------------------------------------------------------------------------
__global__ __launch_bounds__(64, 1) void lstm3_fallback_kernel(
    const float* __restrict__ x,
    const float* __restrict__ Wih1, const float* __restrict__ Whh1,
    const float* __restrict__ bih1, const float* __restrict__ bhh1,
    const float* __restrict__ Wih2, const float* __restrict__ Whh2,
    const float* __restrict__ bih2, const float* __restrict__ bhh2,
    const float* __restrict__ Wih3, const float* __restrict__ Whh3,
    const float* __restrict__ bih3, const float* __restrict__ bhh3,
    const float* __restrict__ mask1, const float* __restrict__ mask2,
    const float* __restrict__ mask3,
    float* __restrict__ out)
{
    const int lane = threadIdx.x;
    const int b = blockIdx.x;

    __shared__ __align__(16) float sh_x[2][F];
    __shared__ __align__(16) float sh_h1[H1];
    __shared__ __align__(16) float sh_h2[H2];
    __shared__ __align__(16) float sh_h3[H3];

    const int r0 = lane, r1 = lane + 64;
    float wi1a[F], wh1a[H1], wi1b[F], wh1b[H1];
#pragma unroll
    for (int k = 0; k < F; ++k) { wi1a[k] = Wih1[r0 * F + k]; wi1b[k] = Wih1[r1 * F + k]; }
#pragma unroll
    for (int k = 0; k < H1; ++k) { wh1a[k] = Whh1[r0 * H1 + k]; wh1b[k] = Whh1[r1 * H1 + k]; }
    const float bias0 = bih1[r0] + bhh1[r0];
    const float bias1 = bih1[r1] + bhh1[r1];
    const float cm1b = (lane < 32) ? 2.0f * SIG_CM : SIG_CM;
    const float ka1b = (lane < 32) ? 2.0f : 1.0f;
    const float kb1b = (lane < 32) ? -1.0f : 0.0f;

    const int r2 = lane & 31;
    float wi2[H1], wh2[H2];
#pragma unroll
    for (int k = 0; k < H1; ++k) wi2[k] = Wih2[r2 * H1 + k] * mask1[b * H1 + k];
#pragma unroll
    for (int k = 0; k < H2; ++k) wh2[k] = Whh2[r2 * H2 + k];
    const float bias2 = bih2[r2] + bhh2[r2];
    const int sec2 = r2 >> 3;
    const float cm2 = (sec2 == 2) ? 2.0f * SIG_CM : SIG_CM;
    const float ka2 = (sec2 == 2) ? 2.0f : 1.0f;
    const float kb2 = (sec2 == 2) ? -1.0f : 0.0f;

    float wi3[H2], wh3[H3];
#pragma unroll
    for (int k = 0; k < H2; ++k) wi3[k] = Wih3[r2 * H2 + k] * mask2[b * H2 + k];
#pragma unroll
    for (int k = 0; k < H3; ++k) wh3[k] = Whh3[r2 * H3 + k];
    const float bias3 = bih3[r2] + bhh3[r2];

    const float m3 = mask3[b * H3 + (lane & 7)];

    float c1 = 0.f, c2 = 0.f, c3 = 0.f;
    if (lane < F) sh_x[0][lane] = x[b * F + lane];
    if (lane < H1) sh_h1[lane] = 0.f;
    if (lane < H2) sh_h2[lane] = 0.f;
    if (lane < H3) sh_h3[lane] = 0.f;
    WAVE_SYNC();

    const int j = lane & 7;

    for (int t = 0; t < T; ++t) {
        const int cur = t & 1, nxt = cur ^ 1;
        float xnext = 0.f;
        {
            const int tn = (t + 1 < T) ? (t + 1) : t;
            if (lane < F) xnext = x[tn * (B * F) + b * F + lane];
        }
        float a0x = 0.f, a0h = 0.f, a1x = 0.f, a1h = 0.f;
        {
            const float4* xp = (const float4*)sh_x[cur];
            const float4* hp = (const float4*)sh_h1;
#pragma unroll
            for (int q = 0; q < 8; ++q) {
                float4 xv = xp[q], hv = hp[q];
                FMA4(a0x, wi1a, xv, 4 * q);
                FMA4(a0h, wh1a, hv, 4 * q);
                FMA4(a1x, wi1b, xv, 4 * q);
                FMA4(a1h, wh1b, hv, 4 * q);
            }
        }
        const float a0 = bias0 + a0x + a0h;
        const float a1 = bias1 + a1x + a1h;
        const float g0 = act_f(a0, SIG_CM, 1.0f, 0.0f);
        const float g1 = act_f(a1, cm1b, ka1b, kb1b);
        const float f_ = __shfl_xor(g0, 32);
        const float o_ = __shfl_xor(g1, 32);
        c1 = fmaf(f_, c1, g0 * g1);
        const float h1 = o_ * tanh_fast(c1);

        WAVE_SYNC();
        if (lane < H1) sh_h1[lane] = h1;
        if (lane < F) sh_x[nxt][lane] = xnext;
        WAVE_SYNC();

        float a2x = 0.f, a2h = 0.f;
        {
            const float4* hp = (const float4*)sh_h1;
#pragma unroll
            for (int q = 0; q < 8; ++q) { float4 hv = hp[q]; FMA4(a2x, wi2, hv, 4 * q); }
            const float4* h2p = (const float4*)sh_h2;
            float4 v0 = h2p[0], v1 = h2p[1];
            FMA4(a2h, wh2, v0, 0);
            FMA4(a2h, wh2, v1, 4);
        }
        const float a2 = bias2 + a2x + a2h;
        const float r2v = act_f(a2, cm2, ka2, kb2);
        const float i2 = __shfl(r2v, j);
        const float f2 = __shfl(r2v, j + 8);
        const float g2 = __shfl(r2v, j + 16);
        const float o2 = __shfl(r2v, j + 24);
        c2 = fmaf(f2, c2, i2 * g2);
        const float h2 = o2 * tanh_fast(c2);

        WAVE_SYNC();
        if (lane < H2) sh_h2[lane] = h2;
        WAVE_SYNC();

        float a3x = 0.f, a3h = 0.f;
        {
            const float4* h2p = (const float4*)sh_h2;
            const float4* h3p = (const float4*)sh_h3;
            float4 u0 = h2p[0], u1 = h2p[1];
            FMA4(a3x, wi3, u0, 0);
            FMA4(a3x, wi3, u1, 4);
            float4 w0 = h3p[0], w1 = h3p[1];
            FMA4(a3h, wh3, w0, 0);
            FMA4(a3h, wh3, w1, 4);
        }
        const float a3 = bias3 + a3x + a3h;
        const float r3v = act_f(a3, cm2, ka2, kb2);
        const float i3 = __shfl(r3v, j);
        const float f3 = __shfl(r3v, j + 8);
        const float g3 = __shfl(r3v, j + 16);
        const float o3 = __shfl(r3v, j + 24);
        c3 = fmaf(f3, c3, i3 * g3);
        const float h3 = o3 * tanh_fast(c3);

        if (lane < H3) out[t * (B * H3) + b * H3 + lane] = h3 * m3;

        WAVE_SYNC();
        if (lane < H3) sh_h3[lane] = h3;
        WAVE_SYNC();
    }
}

extern "C" void kernel_launch(void* const* d_in, const int* in_sizes, int n_in,
                              void* d_out, int out_size, void* d_ws, size_t ws_size,
                              hipStream_t stream) {
    (void)in_sizes; (void)n_in; (void)out_size;
    const float* x     = (const float*)d_in[0];
    const float* Wih1  = (const float*)d_in[1];
    const float* Whh1  = (const float*)d_in[2];
    const float* bih1  = (const float*)d_in[3];
    const float* bhh1  = (const float*)d_in[4];
    const float* Wih2  = (const float*)d_in[5];
    const float* Whh2  = (const float*)d_in[6];
    const float* bih2  = (const float*)d_in[7];
    const float* bhh2  = (const float*)d_in[8];
    const float* Wih3  = (const float*)d_in[9];
    const float* Whh3  = (const float*)d_in[10];
    const float* bih3  = (const float*)d_in[11];
    const float* bhh3  = (const float*)d_in[12];
    const float* mask1 = (const float*)d_in[13];
    const float* mask2 = (const float*)d_in[14];
    const float* mask3 = (const float*)d_in[15];
    float* out = (float*)d_out;

    const size_t xg_bytes = (size_t)T * B * G1 * sizeof(float);  // 256 MB
    if (ws_size >= xg_bytes) {
        float* xg = (float*)d_ws;
        xg_kernel<<<dim3(T * B / GPB), dim3(128), 0, stream>>>(
            x, Wih1, bih1, bhh1, xg);
        lstm3_rec_kernel<<<dim3(B), dim3(192), 0, stream>>>(
            xg, Whh1, Wih2, Whh2, bih2, bhh2,
            Wih3, Whh3, bih3, bhh3, mask1, mask2, mask3, out);
    } else {
        lstm3_fallback_kernel<<<dim3(B), dim3(64), 0, stream>>>(
            x, Wih1, Whh1, bih1, bhh1, Wih2, Whh2, bih2, bhh2,
            Wih3, Whh3, bih3, bhh3, mask1, mask2, mask3, out);
    }
}